// Round 1
// baseline (666.889 us; speedup 1.0000x reference)
//
#include <hip/hip_runtime.h>
#include <hip/hip_bf16.h>

// ---------------------------------------------------------------------------
// TransformerDecoderLayer on MI355X: bf16 MFMA GEMM pipeline, f32 accumulate.
// B=4 L=1024 D=512 H=8 F=2048.  All GEMMs are NT (C = A * B^T), A [M,K],
// B [N,K], both row-major bf16.  128x128 tile, 4 waves, 16x16x32 MFMA.
// ---------------------------------------------------------------------------

typedef __attribute__((ext_vector_type(4))) float f32x4;
typedef __attribute__((ext_vector_type(8))) short bf16x8;   // 8 bf16 in 4 VGPRs

#define SCALE 0.04419417382415922f   // 1/sqrt(512)

__device__ __forceinline__ short f2bf(float f) {
  __hip_bfloat16 h = __float2bfloat16(f);
  short s; __builtin_memcpy(&s, &h, 2); return s;
}

__device__ __forceinline__ void gload16(const void* g, void* lds) {
  // async global->LDS, 16B per lane; LDS dest is wave-uniform base + lane*16
  __builtin_amdgcn_global_load_lds(
      (const __attribute__((address_space(1))) unsigned int*)g,
      (__attribute__((address_space(3))) unsigned int*)lds, 16, 0, 0);
}

// ---------------- elementwise converts ----------------
__global__ __launch_bounds__(256) void cvt_f32_bf16(const float* __restrict__ in,
                                                    short* __restrict__ out, int n4) {
  int i = blockIdx.x * 256 + threadIdx.x;
  if (i >= n4) return;
  float4 v = reinterpret_cast<const float4*>(in)[i];
  short4 o; o.x = f2bf(v.x); o.y = f2bf(v.y); o.z = f2bf(v.z); o.w = f2bf(v.w);
  reinterpret_cast<short4*>(out)[i] = o;
}

// wo [512, 4096]: wo_p[o][h*512+d] = wo[o][h2*512 + h*64 + e], d = h2*64+e
// (undoes the reference's reshape/transpose/concat so ctx can stay [B,L,H*D])
__global__ __launch_bounds__(256) void permute_wo(const float* __restrict__ in,
                                                  short* __restrict__ out) {
  int i = blockIdx.x * 256 + threadIdx.x;   // 512*4096
  int o = i >> 12, j = i & 4095;
  int h = j >> 9, d = j & 511;
  int h2 = d >> 6, e = d & 63;
  out[i] = f2bf(in[(o << 12) + h2 * 512 + h * 64 + e]);
}

// ---------------- block reductions (256 threads = 4 waves) ----------------
__device__ __forceinline__ float block_sum(float v, float* sm) {
  #pragma unroll
  for (int o = 1; o < 64; o <<= 1) v += __shfl_xor(v, o, 64);
  int w = threadIdx.x >> 6;
  if ((threadIdx.x & 63) == 0) sm[w] = v;
  __syncthreads();
  float r = sm[0] + sm[1] + sm[2] + sm[3];
  __syncthreads();
  return r;
}
__device__ __forceinline__ float block_max(float v, float* sm) {
  #pragma unroll
  for (int o = 1; o < 64; o <<= 1) v = fmaxf(v, __shfl_xor(v, o, 64));
  int w = threadIdx.x >> 6;
  if ((threadIdx.x & 63) == 0) sm[w] = v;
  __syncthreads();
  float r = fmaxf(fmaxf(sm[0], sm[1]), fmaxf(sm[2], sm[3]));
  __syncthreads();
  return r;
}

// ---------------- layernorm: row of 512, out bf16 ----------------
__global__ __launch_bounds__(256) void ln_rows(const float* __restrict__ in,
    const float* __restrict__ gw, const float* __restrict__ bw,
    short* __restrict__ out) {
  __shared__ float sm[4];
  size_t row = blockIdx.x;
  const float2 v = reinterpret_cast<const float2*>(in + row * 512)[threadIdx.x];
  float mu = block_sum(v.x + v.y, sm) * (1.0f / 512.0f);
  float dx = v.x - mu, dy = v.y - mu;
  float var = block_sum(dx * dx + dy * dy, sm) * (1.0f / 512.0f);
  float rs = rsqrtf(var + 1e-6f);
  int c = threadIdx.x * 2;
  short2 o;
  o.x = f2bf(dx * rs * gw[c] + bw[c]);
  o.y = f2bf(dy * rs * gw[c + 1] + bw[c + 1]);
  reinterpret_cast<short2*>(out + row * 512)[threadIdx.x] = o;
}

// ---------------- softmax: in-place on rows of 1024, optional bf16 P ------
__global__ __launch_bounds__(256) void softmax_rows(float* __restrict__ data,
                                                    short* __restrict__ pout,
                                                    int withP) {
  __shared__ float sm[4];
  size_t row = blockIdx.x;
  float* rp = data + row * 1024;
  float4 v = reinterpret_cast<float4*>(rp)[threadIdx.x];
  float m = block_max(fmaxf(fmaxf(v.x, v.y), fmaxf(v.z, v.w)), sm);
  float e0 = expf(v.x - m), e1 = expf(v.y - m);
  float e2 = expf(v.z - m), e3 = expf(v.w - m);
  float inv = 1.0f / block_sum(e0 + e1 + e2 + e3, sm);
  float4 w; w.x = e0 * inv; w.y = e1 * inv; w.z = e2 * inv; w.w = e3 * inv;
  reinterpret_cast<float4*>(rp)[threadIdx.x] = w;
  if (withP) {
    short4 o; o.x = f2bf(w.x); o.y = f2bf(w.y); o.z = f2bf(w.z); o.w = f2bf(w.w);
    reinterpret_cast<short4*>(pout + row * 1024)[threadIdx.x] = o;
  }
}

// ---------------- generic NT GEMM with fused epilogues ----------------
// EPI 0: QKV   -> q,k [B,H,L,D] bf16 (bout,bout2), v^T [B,H,D,L] bf16 (bout3)
// EPI 1: self logits -> fout (f32, batched), *SCALE, causal -1e9
// EPI 2: P*V   -> comb [B, L, H*D] bf16 (bout)
// EPI 3: sa    -> fout = fin(tokens) + val        (t after attention, f32)
// EPI 4: ffn1  -> bout = bf16(gelu(val + fin[n])) (h1)
// EPI 5: ffn2  -> fout = fin2 + val + fin[n]; bout = bf16(fout)   (final t)
// EPI 6: ck/cq -> bout [B,H,L,D] bf16
// EPI 7: cross logits -> fout (f32, batched), *SCALE
template<int EPI>
__global__ __launch_bounds__(256, 2) void gemm_nt(
    const short* __restrict__ A, const short* __restrict__ Bw,
    int M, int N, int K, long long sA, long long sB,
    const float* __restrict__ fin, const float* __restrict__ fin2,
    float* __restrict__ fout, short* __restrict__ bout,
    short* __restrict__ bout2, short* __restrict__ bout3) {
  __shared__ short As[128 * 32];
  __shared__ short Bs[128 * 32];
  const int tid = threadIdx.x;
  const int w = tid >> 6, l = tid & 63;
  const int wr = w >> 1, wc = w & 1;          // 2x2 wave grid, 64x64 per wave
  const int lr = l & 15, kh = l >> 4;
  const int bm = blockIdx.y * 128, bn = blockIdx.x * 128;
  const int z = blockIdx.z;
  const short* Ab = A + (size_t)z * sA;
  const short* Bb = Bw + (size_t)z * sB;
  const int ar = w * 16 + (l >> 2);           // staging row within 64-row chunk
  const int ac = (l & 3) * 8;                 // staging col (elements)

  f32x4 acc[4][4];
  #pragma unroll
  for (int i = 0; i < 4; ++i)
    #pragma unroll
    for (int j = 0; j < 4; ++j) acc[i][j] = (f32x4){0.f, 0.f, 0.f, 0.f};

  for (int k0 = 0; k0 < K; k0 += 32) {
    #pragma unroll
    for (int c = 0; c < 2; ++c) {
      gload16(Ab + (size_t)(bm + c * 64 + ar) * K + k0 + ac, &As[c * 2048 + w * 512]);
      gload16(Bb + (size_t)(bn + c * 64 + ar) * K + k0 + ac, &Bs[c * 2048 + w * 512]);
    }
    __syncthreads();   // compiler drains vmcnt before s_barrier
    bf16x8 af[4], bfr[4];
    #pragma unroll
    for (int i = 0; i < 4; ++i)
      af[i] = *reinterpret_cast<const bf16x8*>(&As[(wr * 64 + i * 16 + lr) * 32 + kh * 8]);
    #pragma unroll
    for (int j = 0; j < 4; ++j)
      bfr[j] = *reinterpret_cast<const bf16x8*>(&Bs[(wc * 64 + j * 16 + lr) * 32 + kh * 8]);
    #pragma unroll
    for (int i = 0; i < 4; ++i)
      #pragma unroll
      for (int j = 0; j < 4; ++j)
        acc[i][j] = __builtin_amdgcn_mfma_f32_16x16x32_bf16(af[i], bfr[j], acc[i][j], 0, 0, 0);
    __syncthreads();
  }

  // C frag layout (m89-verified): col = lane&15, row = (lane>>4)*4 + r
  #pragma unroll
  for (int i = 0; i < 4; ++i) {
    #pragma unroll
    for (int j = 0; j < 4; ++j) {
      #pragma unroll
      for (int r = 0; r < 4; ++r) {
        const int grow = bm + wr * 64 + i * 16 + kh * 4 + r;
        const int gcol = bn + wc * 64 + j * 16 + lr;
        const float val = acc[i][j][r];
        if constexpr (EPI == 0) {
          const int b = grow >> 10, lw = grow & 1023;
          if (gcol < 4096) {
            const int h = gcol >> 9, o = gcol & 511;
            bout[(((size_t)(b * 8 + h)) * 1024 + lw) * 512 + o] = f2bf(val);
          } else if (gcol < 8192) {
            const int n2 = gcol - 4096, h = n2 >> 9, o = n2 & 511;
            bout2[(((size_t)(b * 8 + h)) * 1024 + lw) * 512 + o] = f2bf(val);
          } else {   // V stored transposed: vt[b,h,o,l]
            const int n2 = gcol - 8192, h = n2 >> 9, o = n2 & 511;
            bout3[(((size_t)(b * 8 + h)) * 512 + o) * 1024 + lw] = f2bf(val);
          }
        } else if constexpr (EPI == 1) {
          fout[(size_t)z * 1048576 + (size_t)grow * 1024 + gcol] =
              val * SCALE + (gcol > grow ? -1.0e9f : 0.0f);
        } else if constexpr (EPI == 2) {
          const int b = z >> 3, h = z & 7;
          bout[((size_t)(b * 1024 + grow)) * 4096 + h * 512 + gcol] = f2bf(val);
        } else if constexpr (EPI == 3) {
          const size_t idx = (size_t)grow * 512 + gcol;
          fout[idx] = fin[idx] + val;
        } else if constexpr (EPI == 4) {
          const float x = val + fin[gcol];
          const float gx = 0.5f * x * (1.0f + erff(x * 0.70710678118654752f));
          bout[(size_t)grow * 2048 + gcol] = f2bf(gx);
        } else if constexpr (EPI == 5) {
          const size_t idx = (size_t)grow * 512 + gcol;
          const float v2 = fin2[idx] + val + fin[gcol];
          fout[idx] = v2;
          bout[idx] = f2bf(v2);
        } else if constexpr (EPI == 6) {
          const int b = grow >> 10, lw = grow & 1023;
          const int h = gcol >> 9, o = gcol & 511;
          bout[(((size_t)(b * 8 + h)) * 1024 + lw) * 512 + o] = f2bf(val);
        } else if constexpr (EPI == 7) {
          fout[(size_t)z * 1048576 + (size_t)grow * 1024 + gcol] = val * SCALE;
        }
      }
    }
  }
}

// ---------------------------------------------------------------------------
extern "C" void kernel_launch(void* const* d_in, const int* in_sizes, int n_in,
                              void* d_out, int out_size, void* d_ws, size_t ws_size,
                              hipStream_t stream) {
  const float* tokens = (const float*)d_in[0];
  // d_in[1] inp_lens: unused by reference. d_in[2] self_mask: causal, applied
  // analytically. d_in[16] cwv: unused by reference outputs.
  const float* ln1g = (const float*)d_in[3];
  const float* ln1b = (const float*)d_in[4];
  const float* ln2g = (const float*)d_in[5];
  const float* ln2b = (const float*)d_in[6];
  const float* wq = (const float*)d_in[7];
  const float* wk = (const float*)d_in[8];
  const float* wv = (const float*)d_in[9];
  const float* wo = (const float*)d_in[10];
  const float* w1 = (const float*)d_in[11];
  const float* b1 = (const float*)d_in[12];
  const float* w2 = (const float*)d_in[13];
  const float* b2 = (const float*)d_in[14];
  const float* cwk = (const float*)d_in[15];
  const float* cwq = (const float*)d_in[17];

  float* out_t = (float*)d_out;             // [B,L,D]        2,097,152 f32
  float* out_self = out_t + 2097152;        // [B,H,L,L]     33,554,432 f32
  float* out_cross = out_self + 33554432;   // [B,H,L,L]

  char* ws = (char*)d_ws;
  size_t off = 0;
  auto alloc = [&](size_t bytes) -> void* {
    void* p = ws + off; off = (off + bytes + 255) & ~(size_t)255; return p;
  };
  short* xb   = (short*)alloc(2097152ull * 2);   // LN1(tokens) bf16
  short* tokb = (short*)alloc(2097152ull * 2);   // tokens bf16
  float* tf   = (float*)alloc(2097152ull * 4);   // t after attention, f32
  short* tb   = (short*)alloc(2097152ull * 2);   // final t bf16
  short* yb   = (short*)alloc(2097152ull * 2);   // LN2(t) bf16
  short* h1b  = (short*)alloc(8388608ull * 2);   // gelu hidden [4096,2048]
  short* qb   = (short*)alloc(16777216ull * 2);  // q [B,H,L,D]
  short* kb   = (short*)alloc(16777216ull * 2);  // k [B,H,L,D]
  short* vtb  = (short*)alloc(16777216ull * 2);  // v^T [B,H,D,L]
  short* Pb   = (short*)alloc(33554432ull * 2);  // softmax probs bf16
  short* comb = (short*)alloc(16777216ull * 2);  // ctx in [B,L,H*D]
  short* Wqkv = (short*)alloc(6291456ull * 2);   // [wq;wk;wv] [12288,512]
  short* wop  = (short*)alloc(2097152ull * 2);   // permuted wo
  short* w1b  = (short*)alloc(1048576ull * 2);
  short* w2b  = (short*)alloc(1048576ull * 2);
  short* cwkb = (short*)alloc(2097152ull * 2);
  short* cwqb = (short*)alloc(2097152ull * 2);
  short* ckb = qb;   // alias: q/k dead after self-attention logits
  short* cqb = kb;

  // weight / input converts
  cvt_f32_bf16<<<2048, 256, 0, stream>>>(tokens, tokb, 524288);
  cvt_f32_bf16<<<2048, 256, 0, stream>>>(wq, Wqkv, 524288);
  cvt_f32_bf16<<<2048, 256, 0, stream>>>(wk, Wqkv + 2097152, 524288);
  cvt_f32_bf16<<<2048, 256, 0, stream>>>(wv, Wqkv + 4194304, 524288);
  permute_wo<<<8192, 256, 0, stream>>>(wo, wop);
  cvt_f32_bf16<<<1024, 256, 0, stream>>>(w1, w1b, 262144);
  cvt_f32_bf16<<<1024, 256, 0, stream>>>(w2, w2b, 262144);
  cvt_f32_bf16<<<2048, 256, 0, stream>>>(cwk, cwkb, 524288);
  cvt_f32_bf16<<<2048, 256, 0, stream>>>(cwq, cwqb, 524288);

  // LN1 -> x
  ln_rows<<<4096, 256, 0, stream>>>(tokens, ln1g, ln1b, xb);
  // QKV projection (stacked weights): [4096,512] x [12288,512]^T
  gemm_nt<0><<<dim3(96, 32, 1), 256, 0, stream>>>(xb, Wqkv, 4096, 12288, 512, 0, 0,
      nullptr, nullptr, nullptr, qb, kb, vtb);
  // self logits (batched over B*H=32), scaled + causal, straight into d_out
  gemm_nt<1><<<dim3(8, 8, 32), 256, 0, stream>>>(qb, kb, 1024, 1024, 512, 524288, 524288,
      nullptr, nullptr, out_self, nullptr, nullptr, nullptr);
  // softmax in place + bf16 P
  softmax_rows<<<32768, 256, 0, stream>>>(out_self, Pb, 1);
  // ctx = P * V  (NT against v^T), write in comb layout
  gemm_nt<2><<<dim3(4, 8, 32), 256, 0, stream>>>(Pb, vtb, 1024, 512, 1024, 1048576, 524288,
      nullptr, nullptr, nullptr, comb, nullptr, nullptr);
  // sa projection + residual: t = tokens + comb*wo_p^T
  gemm_nt<3><<<dim3(4, 32, 1), 256, 0, stream>>>(comb, wop, 4096, 512, 4096, 0, 0,
      tokens, nullptr, tf, nullptr, nullptr, nullptr);
  // FFN
  ln_rows<<<4096, 256, 0, stream>>>(tf, ln2g, ln2b, yb);
  gemm_nt<4><<<dim3(16, 32, 1), 256, 0, stream>>>(yb, w1b, 4096, 2048, 512, 0, 0,
      b1, nullptr, nullptr, h1b, nullptr, nullptr);
  gemm_nt<5><<<dim3(4, 32, 1), 256, 0, stream>>>(h1b, w2b, 4096, 512, 2048, 0, 0,
      b2, tf, out_t, tb, nullptr, nullptr);
  // cross attention: K from original tokens, Q from final t
  gemm_nt<6><<<dim3(32, 32, 1), 256, 0, stream>>>(tokb, cwkb, 4096, 4096, 512, 0, 0,
      nullptr, nullptr, nullptr, ckb, nullptr, nullptr);
  gemm_nt<6><<<dim3(32, 32, 1), 256, 0, stream>>>(tb, cwqb, 4096, 4096, 512, 0, 0,
      nullptr, nullptr, nullptr, cqb, nullptr, nullptr);
  gemm_nt<7><<<dim3(8, 8, 32), 256, 0, stream>>>(cqb, ckb, 1024, 1024, 512, 524288, 524288,
      nullptr, nullptr, out_cross, nullptr, nullptr, nullptr);
  softmax_rows<<<32768, 256, 0, stream>>>(out_cross, nullptr, 0);
}

// Round 2
// 631.466 us; speedup vs baseline: 1.0561x; 1.0561x over previous
//
#include <hip/hip_runtime.h>
#include <hip/hip_bf16.h>

// ---------------------------------------------------------------------------
// TransformerDecoderLayer on MI355X: bf16 MFMA GEMM pipeline, f32 accumulate.
// B=4 L=1024 D=512 H=8 F=2048.  All GEMMs are NT (C = A * B^T), A [M,K],
// B [N,K], both row-major bf16.  128xBN tile, 4 waves, 16x16x32 MFMA.
// Swapped-operand MFMA: mfma(b_frag, a_frag) -> lane owns 1 row x 4 cols
// so epilogue stores are short4/float4.
// ---------------------------------------------------------------------------

typedef __attribute__((ext_vector_type(4))) float f32x4;
typedef __attribute__((ext_vector_type(8))) short bf16x8;   // 8 bf16 in 4 VGPRs

#define SCALE 0.04419417382415922f   // 1/sqrt(512)

__device__ __forceinline__ short f2bf(float f) {
  __hip_bfloat16 h = __float2bfloat16(f);
  short s; __builtin_memcpy(&s, &h, 2); return s;
}

__device__ __forceinline__ void gload16(const void* g, void* lds) {
  // async global->LDS, 16B per lane; LDS dest is wave-uniform base + lane*16
  __builtin_amdgcn_global_load_lds(
      (const __attribute__((address_space(1))) unsigned int*)g,
      (__attribute__((address_space(3))) unsigned int*)lds, 16, 0, 0);
}

// ---------------- fused weight converts ----------------
// wq,wk,wv -> Wqkv (contiguous [12288,512]); w1,w2,cwk,cwq -> bf16
__global__ __launch_bounds__(256) void cvt_multi(
    const float* __restrict__ s0, const float* __restrict__ s1,
    const float* __restrict__ s2, const float* __restrict__ s3,
    const float* __restrict__ s4, const float* __restrict__ s5,
    const float* __restrict__ s6,
    short* __restrict__ Wqkv, short* __restrict__ w1b, short* __restrict__ w2b,
    short* __restrict__ cwkb, short* __restrict__ cwqb) {
  int i = blockIdx.x * 256 + threadIdx.x;   // 3,145,728 float4 jobs
  const float* src; short* dst; int k;
  if (i < 524288)       { src = s0; dst = Wqkv;           k = i; }
  else if (i < 1048576) { src = s1; dst = Wqkv + 2097152; k = i - 524288; }
  else if (i < 1572864) { src = s2; dst = Wqkv + 4194304; k = i - 1048576; }
  else if (i < 1835008) { src = s3; dst = w1b;            k = i - 1572864; }
  else if (i < 2097152) { src = s4; dst = w2b;            k = i - 1835008; }
  else if (i < 2621440) { src = s5; dst = cwkb;           k = i - 2097152; }
  else                  { src = s6; dst = cwqb;           k = i - 2621440; }
  float4 v = reinterpret_cast<const float4*>(src)[k];
  short4 o; o.x = f2bf(v.x); o.y = f2bf(v.y); o.z = f2bf(v.z); o.w = f2bf(v.w);
  reinterpret_cast<short4*>(dst)[k] = o;
}

// wo [512, 4096]: wo_p[o][h*512+d] = wo[o][h2*512 + h*64 + e], d = h2*64+e
__global__ __launch_bounds__(256) void permute_wo(const float* __restrict__ in,
                                                  short* __restrict__ out) {
  int i = blockIdx.x * 256 + threadIdx.x;   // 512*4096
  int o = i >> 12, j = i & 4095;
  int h = j >> 9, d = j & 511;
  int h2 = d >> 6, e = d & 63;
  out[i] = f2bf(in[(o << 12) + h2 * 512 + h * 64 + e]);
}

// ---------------- block reductions (256 threads = 4 waves) ----------------
__device__ __forceinline__ float block_sum(float v, float* sm) {
  #pragma unroll
  for (int o = 1; o < 64; o <<= 1) v += __shfl_xor(v, o, 64);
  int w = threadIdx.x >> 6;
  if ((threadIdx.x & 63) == 0) sm[w] = v;
  __syncthreads();
  float r = sm[0] + sm[1] + sm[2] + sm[3];
  __syncthreads();
  return r;
}
__device__ __forceinline__ float block_max(float v, float* sm) {
  #pragma unroll
  for (int o = 1; o < 64; o <<= 1) v = fmaxf(v, __shfl_xor(v, o, 64));
  int w = threadIdx.x >> 6;
  if ((threadIdx.x & 63) == 0) sm[w] = v;
  __syncthreads();
  float r = fmaxf(fmaxf(sm[0], sm[1]), fmaxf(sm[2], sm[3]));
  __syncthreads();
  return r;
}

// ---------------- layernorm: row of 512, out bf16 (+optional raw bf16) ----
__global__ __launch_bounds__(256) void ln_rows(const float* __restrict__ in,
    const float* __restrict__ gw, const float* __restrict__ bw,
    short* __restrict__ out, short* __restrict__ rawout) {
  __shared__ float sm[4];
  size_t row = blockIdx.x;
  const float2 v = reinterpret_cast<const float2*>(in + row * 512)[threadIdx.x];
  if (rawout) {
    short2 ro; ro.x = f2bf(v.x); ro.y = f2bf(v.y);
    reinterpret_cast<short2*>(rawout + row * 512)[threadIdx.x] = ro;
  }
  float mu = block_sum(v.x + v.y, sm) * (1.0f / 512.0f);
  float dx = v.x - mu, dy = v.y - mu;
  float var = block_sum(dx * dx + dy * dy, sm) * (1.0f / 512.0f);
  float rs = rsqrtf(var + 1e-6f);
  int c = threadIdx.x * 2;
  short2 o;
  o.x = f2bf(dx * rs * gw[c] + bw[c]);
  o.y = f2bf(dy * rs * gw[c + 1] + bw[c + 1]);
  reinterpret_cast<short2*>(out + row * 512)[threadIdx.x] = o;
}

// ---------------- softmax rows of 1024, in place, optional bf16 P ---------
// CAUSAL: cols > (row&1023) are known-masked; never read (GEMM skipped those
// tiles), write exact 0.0 to W and P — matches exp(-1e9 - m) == 0.0f.
template<int CAUSAL>
__global__ __launch_bounds__(256) void softmax_rows(float* __restrict__ data,
                                                    short* __restrict__ pout,
                                                    int withP) {
  __shared__ float sm[4];
  size_t row = blockIdx.x;
  const int r = (int)(row & 1023);
  float* rp = data + row * 1024;
  const int c0 = threadIdx.x * 4;
  float4 v;
  bool live = true;
  if (CAUSAL) {
    live = (c0 <= r);
    if (live) {
      v = reinterpret_cast<float4*>(rp)[threadIdx.x];
      if (c0 + 1 > r) v.y = -1.0e9f;
      if (c0 + 2 > r) v.z = -1.0e9f;
      if (c0 + 3 > r) v.w = -1.0e9f;
    } else {
      v.x = v.y = v.z = v.w = -1.0e9f;
    }
  } else {
    v = reinterpret_cast<float4*>(rp)[threadIdx.x];
  }
  float lm = live ? fmaxf(fmaxf(v.x, v.y), fmaxf(v.z, v.w)) : -1.0e30f;
  float m = block_max(lm, sm);
  float e0 = 0.f, e1 = 0.f, e2 = 0.f, e3 = 0.f;
  if (live) {
    e0 = expf(v.x - m); e1 = expf(v.y - m);
    e2 = expf(v.z - m); e3 = expf(v.w - m);
  }
  float inv = 1.0f / block_sum(e0 + e1 + e2 + e3, sm);
  float4 w; w.x = e0 * inv; w.y = e1 * inv; w.z = e2 * inv; w.w = e3 * inv;
  reinterpret_cast<float4*>(rp)[threadIdx.x] = w;
  if (withP) {
    short4 o; o.x = f2bf(w.x); o.y = f2bf(w.y); o.z = f2bf(w.z); o.w = f2bf(w.w);
    reinterpret_cast<short4*>(pout + row * 1024)[threadIdx.x] = o;
  }
}

// ---------------- generic NT GEMM with fused epilogues ----------------
// EPI 0: QKV   -> q,k [B,H,L,D] bf16 (bout,bout2), v^T [B,H,D,L] bf16 (bout3)
// EPI 1: self logits (triangular tile grid) -> fout f32, *SCALE, causal -1e9
// EPI 2: P*V   -> comb [B,L,H*D] bf16; K-loop truncated to bm+128 (P causal)
// EPI 3: sa    -> fout = fin(tokens) + val    (BN=64)
// EPI 4: ffn1  -> bout = bf16(gelu(val + fin[n]))
// EPI 5: ffn2  -> fout = fin2 + val + fin[n]; bout = bf16(fout)   (BN=64)
// EPI 6: ck/cq batched via z: z==0 -> A,Bw;  z==1 -> A2,B2; out += z*16M
// EPI 7: cross logits -> fout f32, *SCALE
template<int EPI, int BN>
__global__ __launch_bounds__(256, 2) void gemm_nt(
    const short* __restrict__ A, const short* __restrict__ Bw,
    int K, long long sA, long long sB,
    const float* __restrict__ fin, const float* __restrict__ fin2,
    float* __restrict__ fout, short* __restrict__ bout,
    short* __restrict__ bout2, short* __restrict__ bout3,
    const short* __restrict__ A2, const short* __restrict__ B2) {
  constexpr int NJ = BN / 32;               // N-frags per wave
  __shared__ short As[128 * 32];
  __shared__ short Bs[BN * 32];
  const int tid = threadIdx.x;
  const int w = tid >> 6, l = tid & 63;
  const int wr = w >> 1, wc = w & 1;        // 2x2 wave grid
  const int lr = l & 15, kh = l >> 4;
  int bx = blockIdx.x, by = blockIdx.y;
  const int z = blockIdx.z;
  if constexpr (EPI == 1) {                 // triangular decode: idx -> (bx<=by)
    int idx = blockIdx.x;
    by = (int)((sqrtf(8.0f * idx + 1.0f) - 1.0f) * 0.5f);
    while ((by + 1) * (by + 2) / 2 <= idx) ++by;
    while (by * (by + 1) / 2 > idx) --by;
    bx = idx - by * (by + 1) / 2;
  }
  const int bm = by * 128, bn = bx * BN;
  const short* Ab; const short* Bb;
  if constexpr (EPI == 6) { Ab = z ? A2 : A; Bb = z ? B2 : Bw; }
  else { Ab = A + (size_t)z * sA; Bb = Bw + (size_t)z * sB; }
  const int ar = w * 16 + (l >> 2);         // staging row within 64-row chunk
  const int ac = (l & 3) * 8;               // staging col (elements)

  f32x4 acc[4][NJ];
  #pragma unroll
  for (int i = 0; i < 4; ++i)
    #pragma unroll
    for (int j = 0; j < NJ; ++j) acc[i][j] = (f32x4){0.f, 0.f, 0.f, 0.f};

  const int kend = (EPI == 2) ? (bm + 128) : K;   // P causal: cols>row are 0
  for (int k0 = 0; k0 < kend; k0 += 32) {
    #pragma unroll
    for (int c = 0; c < 2; ++c)
      gload16(Ab + (size_t)(bm + c * 64 + ar) * K + k0 + ac, &As[c * 2048 + w * 512]);
    #pragma unroll
    for (int c = 0; c < BN / 64; ++c)
      gload16(Bb + (size_t)(bn + c * 64 + ar) * K + k0 + ac, &Bs[c * 2048 + w * 512]);
    __syncthreads();   // compiler drains vmcnt before s_barrier
    bf16x8 af[4], bfr[NJ];
    #pragma unroll
    for (int i = 0; i < 4; ++i)
      af[i] = *reinterpret_cast<const bf16x8*>(&As[(wr * 64 + i * 16 + lr) * 32 + kh * 8]);
    #pragma unroll
    for (int j = 0; j < NJ; ++j)
      bfr[j] = *reinterpret_cast<const bf16x8*>(&Bs[(wc * (BN / 2) + j * 16 + lr) * 32 + kh * 8]);
    #pragma unroll
    for (int i = 0; i < 4; ++i)
      #pragma unroll
      for (int j = 0; j < NJ; ++j)
        acc[i][j] = __builtin_amdgcn_mfma_f32_16x16x32_bf16(bfr[j], af[i], acc[i][j], 0, 0, 0);
    __syncthreads();
  }

  // Swapped-operand C layout: M = lane&15 field, N = (lane>>4)*4 + reg field.
  // Lane owns 1 row (grow) x 4 consecutive cols (gcol0..gcol0+3).
  #pragma unroll
  for (int i = 0; i < 4; ++i) {
    const int grow = bm + wr * 64 + i * 16 + lr;
    #pragma unroll
    for (int j = 0; j < NJ; ++j) {
      const int gcol0 = bn + wc * (BN / 2) + j * 16 + kh * 4;
      const float v0 = acc[i][j][0], v1 = acc[i][j][1];
      const float v2 = acc[i][j][2], v3 = acc[i][j][3];
      if constexpr (EPI == 0) {
        const int b = grow >> 10, lw = grow & 1023;
        if (bn < 4096) {
          const int h = gcol0 >> 9, o = gcol0 & 511;
          *reinterpret_cast<short4*>(&bout[(((size_t)(b * 8 + h)) * 1024 + lw) * 512 + o]) =
              make_short4(f2bf(v0), f2bf(v1), f2bf(v2), f2bf(v3));
        } else if (bn < 8192) {
          const int n2 = gcol0 - 4096, h = n2 >> 9, o = n2 & 511;
          *reinterpret_cast<short4*>(&bout2[(((size_t)(b * 8 + h)) * 1024 + lw) * 512 + o]) =
              make_short4(f2bf(v0), f2bf(v1), f2bf(v2), f2bf(v3));
        } else {   // V transposed: vt[b,h,o,l]
          const int n2 = gcol0 - 8192, h = n2 >> 9, o = n2 & 511;
          const size_t base = ((size_t)(b * 8 + h)) * 512;
          bout3[(base + o + 0) * 1024 + lw] = f2bf(v0);
          bout3[(base + o + 1) * 1024 + lw] = f2bf(v1);
          bout3[(base + o + 2) * 1024 + lw] = f2bf(v2);
          bout3[(base + o + 3) * 1024 + lw] = f2bf(v3);
        }
      } else if constexpr (EPI == 1) {
        float4 f;
        f.x = v0 * SCALE + (gcol0 + 0 > grow ? -1.0e9f : 0.0f);
        f.y = v1 * SCALE + (gcol0 + 1 > grow ? -1.0e9f : 0.0f);
        f.z = v2 * SCALE + (gcol0 + 2 > grow ? -1.0e9f : 0.0f);
        f.w = v3 * SCALE + (gcol0 + 3 > grow ? -1.0e9f : 0.0f);
        *reinterpret_cast<float4*>(&fout[(size_t)z * 1048576 + (size_t)grow * 1024 + gcol0]) = f;
      } else if constexpr (EPI == 2) {
        const int b = z >> 3, h = z & 7;
        *reinterpret_cast<short4*>(&bout[((size_t)(b * 1024 + grow)) * 4096 + h * 512 + gcol0]) =
            make_short4(f2bf(v0), f2bf(v1), f2bf(v2), f2bf(v3));
      } else if constexpr (EPI == 3) {
        const size_t idx = (size_t)grow * 512 + gcol0;
        const float4 t4 = *reinterpret_cast<const float4*>(&fin[idx]);
        float4 f; f.x = t4.x + v0; f.y = t4.y + v1; f.z = t4.z + v2; f.w = t4.w + v3;
        *reinterpret_cast<float4*>(&fout[idx]) = f;
      } else if constexpr (EPI == 4) {
        const float4 b4 = *reinterpret_cast<const float4*>(&fin[gcol0]);
        const float x0 = v0 + b4.x, x1 = v1 + b4.y, x2 = v2 + b4.z, x3 = v3 + b4.w;
        const float g0 = 0.5f * x0 * (1.0f + erff(x0 * 0.70710678118654752f));
        const float g1 = 0.5f * x1 * (1.0f + erff(x1 * 0.70710678118654752f));
        const float g2 = 0.5f * x2 * (1.0f + erff(x2 * 0.70710678118654752f));
        const float g3 = 0.5f * x3 * (1.0f + erff(x3 * 0.70710678118654752f));
        *reinterpret_cast<short4*>(&bout[(size_t)grow * 2048 + gcol0]) =
            make_short4(f2bf(g0), f2bf(g1), f2bf(g2), f2bf(g3));
      } else if constexpr (EPI == 5) {
        const size_t idx = (size_t)grow * 512 + gcol0;
        const float4 a4 = *reinterpret_cast<const float4*>(&fin2[idx]);
        const float4 b4 = *reinterpret_cast<const float4*>(&fin[gcol0]);
        float4 f;
        f.x = a4.x + v0 + b4.x; f.y = a4.y + v1 + b4.y;
        f.z = a4.z + v2 + b4.z; f.w = a4.w + v3 + b4.w;
        *reinterpret_cast<float4*>(&fout[idx]) = f;
        *reinterpret_cast<short4*>(&bout[idx]) =
            make_short4(f2bf(f.x), f2bf(f.y), f2bf(f.z), f2bf(f.w));
      } else if constexpr (EPI == 6) {
        const int b = grow >> 10, lw = grow & 1023;
        const int h = gcol0 >> 9, o = gcol0 & 511;
        short* bo = bout + (size_t)z * 16777216;
        *reinterpret_cast<short4*>(&bo[(((size_t)(b * 8 + h)) * 1024 + lw) * 512 + o]) =
            make_short4(f2bf(v0), f2bf(v1), f2bf(v2), f2bf(v3));
      } else if constexpr (EPI == 7) {
        float4 f; f.x = v0 * SCALE; f.y = v1 * SCALE; f.z = v2 * SCALE; f.w = v3 * SCALE;
        *reinterpret_cast<float4*>(&fout[(size_t)z * 1048576 + (size_t)grow * 1024 + gcol0]) = f;
      }
    }
  }
}

// ---------------------------------------------------------------------------
extern "C" void kernel_launch(void* const* d_in, const int* in_sizes, int n_in,
                              void* d_out, int out_size, void* d_ws, size_t ws_size,
                              hipStream_t stream) {
  const float* tokens = (const float*)d_in[0];
  // d_in[1] inp_lens: unused. d_in[2] self_mask: causal, applied analytically.
  // d_in[16] cwv: unused by reference outputs.
  const float* ln1g = (const float*)d_in[3];
  const float* ln1b = (const float*)d_in[4];
  const float* ln2g = (const float*)d_in[5];
  const float* ln2b = (const float*)d_in[6];
  const float* wq = (const float*)d_in[7];
  const float* wk = (const float*)d_in[8];
  const float* wv = (const float*)d_in[9];
  const float* wo = (const float*)d_in[10];
  const float* w1 = (const float*)d_in[11];
  const float* b1 = (const float*)d_in[12];
  const float* w2 = (const float*)d_in[13];
  const float* b2 = (const float*)d_in[14];
  const float* cwk = (const float*)d_in[15];
  const float* cwq = (const float*)d_in[17];

  float* out_t = (float*)d_out;             // [B,L,D]
  float* out_self = out_t + 2097152;        // [B,H,L,L]
  float* out_cross = out_self + 33554432;   // [B,H,L,L]

  char* ws = (char*)d_ws;
  size_t off = 0;
  auto alloc = [&](size_t bytes) -> void* {
    void* p = ws + off; off = (off + bytes + 255) & ~(size_t)255; return p;
  };
  short* xb   = (short*)alloc(2097152ull * 2);   // LN1(tokens) bf16
  short* tokb = (short*)alloc(2097152ull * 2);   // tokens bf16
  float* tf   = (float*)alloc(2097152ull * 4);   // t after attention, f32
  short* tb   = (short*)alloc(2097152ull * 2);   // final t bf16
  short* yb   = (short*)alloc(2097152ull * 2);   // LN2(t) bf16
  short* h1b  = (short*)alloc(8388608ull * 2);   // gelu hidden [4096,2048]
  short* qb   = (short*)alloc(16777216ull * 2);  // q [B,H,L,D]
  short* kb   = (short*)alloc(16777216ull * 2);  // k [B,H,L,D] (contig after qb)
  short* vtb  = (short*)alloc(16777216ull * 2);  // v^T [B,H,D,L]
  short* Pb   = (short*)alloc(33554432ull * 2);  // softmax probs bf16
  short* comb = (short*)alloc(16777216ull * 2);  // ctx in [B,L,H*D]
  short* Wqkv = (short*)alloc(6291456ull * 2);   // [wq;wk;wv] [12288,512]
  short* wop  = (short*)alloc(2097152ull * 2);   // permuted wo
  short* w1b  = (short*)alloc(1048576ull * 2);
  short* w2b  = (short*)alloc(1048576ull * 2);
  short* cwkb = (short*)alloc(2097152ull * 2);
  short* cwqb = (short*)alloc(2097152ull * 2);
  short* ckb = qb;   // alias: q/k dead after self-attention logits
  short* cqb = kb;   // cqb == ckb + 16777216 (contiguous)

  cvt_multi<<<12288, 256, 0, stream>>>(wq, wk, wv, w1, w2, cwk, cwq,
                                       Wqkv, w1b, w2b, cwkb, cwqb);
  permute_wo<<<8192, 256, 0, stream>>>(wo, wop);
  // LN1 -> x (also emits tokens as bf16)
  ln_rows<<<4096, 256, 0, stream>>>(tokens, ln1g, ln1b, xb, tokb);
  // QKV projection: [4096,512] x [12288,512]^T
  gemm_nt<0, 128><<<dim3(96, 32, 1), 256, 0, stream>>>(xb, Wqkv, 512, 0, 0,
      nullptr, nullptr, nullptr, qb, kb, vtb, nullptr, nullptr);
  // self logits: triangular tile grid (36 tiles) x 32 batch-heads
  gemm_nt<1, 128><<<dim3(36, 1, 32), 256, 0, stream>>>(qb, kb, 512, 524288, 524288,
      nullptr, nullptr, out_self, nullptr, nullptr, nullptr, nullptr, nullptr);
  softmax_rows<1><<<32768, 256, 0, stream>>>(out_self, Pb, 1);
  // ctx = P * V (NT against v^T), K truncated per row-tile (P causal zeros)
  gemm_nt<2, 128><<<dim3(4, 8, 32), 256, 0, stream>>>(Pb, vtb, 1024, 1048576, 524288,
      nullptr, nullptr, nullptr, comb, nullptr, nullptr, nullptr, nullptr);
  // sa projection + residual: t = tokens + comb*wo_p^T
  gemm_nt<3, 64><<<dim3(8, 32, 1), 256, 0, stream>>>(comb, wop, 4096, 0, 0,
      tokens, nullptr, tf, nullptr, nullptr, nullptr, nullptr, nullptr);
  ln_rows<<<4096, 256, 0, stream>>>(tf, ln2g, ln2b, yb, nullptr);
  gemm_nt<4, 128><<<dim3(16, 32, 1), 256, 0, stream>>>(yb, w1b, 512, 0, 0,
      b1, nullptr, nullptr, h1b, nullptr, nullptr, nullptr, nullptr);
  gemm_nt<5, 64><<<dim3(8, 32, 1), 256, 0, stream>>>(h1b, w2b, 2048, 0, 0,
      b2, tf, out_t, tb, nullptr, nullptr, nullptr, nullptr);
  // cross attention K and Q projections batched (z=0: tokens*cwk, z=1: t*cwq)
  gemm_nt<6, 128><<<dim3(32, 32, 2), 256, 0, stream>>>(tokb, cwkb, 512, 0, 0,
      nullptr, nullptr, nullptr, ckb, nullptr, nullptr, tb, cwqb);
  gemm_nt<7, 128><<<dim3(8, 8, 32), 256, 0, stream>>>(cqb, ckb, 512, 524288, 524288,
      nullptr, nullptr, out_cross, nullptr, nullptr, nullptr, nullptr, nullptr);
  softmax_rows<0><<<32768, 256, 0, stream>>>(out_cross, nullptr, 0);
}